// Round 7
// baseline (135.190 us; speedup 1.0000x reference)
//
#include <hip/hip_runtime.h>

// CondConv2d: N=8, C_IN=C_OUT=64, H=W=128, K=4 experts, 3x3, pad 1, stride 1.
// f32 in/out; bf16 MFMA compute with f32 accumulate.
// Identity: out = conv2d(x, conv_w + sum_k att[n,k]*weight[k]) + conv_b
// Routing logits = closed-form box-sums of x (mean-pooled C=1 3D convs).
// Pipeline (3 dispatches, no intermediate x transpose buffer):
//   kR : routing stats per (n,h) row -> part   (read-only pass over x)
//   kW : reduce part -> att -> Weff[n][s][co][ci] bf16
//   kC : MFMA conv; stages B directly from f32 x with in-register 8x8
//        f32->bf16 transpose into LDS. 64co x (4h x 64w) tiles.
// NOTE: hipLaunchCooperativeKernel fails under the harness graph capture
// (silent no-op, R5) — regular dispatches only.

typedef unsigned short ushort_t;
typedef __attribute__((ext_vector_type(8))) short bf16x8;
typedef __attribute__((ext_vector_type(4))) float f32x4;

__device__ __forceinline__ ushort_t f2bf(float f) {
    unsigned u = __float_as_uint(f);
    unsigned r = (u + 0x7fffu + ((u >> 16) & 1u)) >> 16;   // RNE
    return (ushort_t)r;
}

// ---------------------------------------------------------------------------
// kR: block per (n,h). Thread (ci8=tid>>5, wg=tid&31) loads 8 float4 (one per
// ci in its group), shuffle-reduces row sums + boundary cols -> part[row*16+q].
__global__ __launch_bounds__(256) void kR(const float* __restrict__ x,
                                          float* __restrict__ part) {
    int row = blockIdx.x;                 // n*128 + h
    int h = row & 127, n = row >> 7;
    int tid = threadIdx.x;
    int wg = tid & 31;                    // float4 lane (w = wg*4 .. +3)
    int ci8 = tid >> 5;                   // 0..7

    __shared__ float catloc[15];
    if (tid < 15) catloc[tid] = 0.f;
    __syncthreads();

    const float* xp = x + (size_t)(n * 64 + ci8 * 8) * 16384 + h * 128 + wg * 4;
#pragma unroll
    for (int j = 0; j < 8; ++j) {
        float4 v = *(const float4*)(xp + (size_t)j * 16384);
        float rs = v.x + v.y + v.z + v.w;
#pragma unroll
        for (int m = 1; m <= 16; m <<= 1) rs += __shfl_xor(rs, m);
        int ci = ci8 * 8 + j;
        int cd = (ci == 0) ? 0 : (ci == 1) ? 1 : (ci == 62) ? 3 : (ci == 63) ? 4 : 2;
        if (wg == 0) {
            atomicAdd(&catloc[cd * 3 + 0], rs);
            atomicAdd(&catloc[cd * 3 + 1], v.x);            // w == 0
        }
        if (wg == 31) atomicAdd(&catloc[cd * 3 + 2], v.w);  // w == 127
    }
    __syncthreads();
    if (tid < 15) part[row * 16 + tid] = catloc[tid];
}

// ---------------------------------------------------------------------------
// kW: block per (n,s). Reduce part rows -> cat; 45 box-sums in parallel;
// logits+softmax; Weff[n][s][co][ci] = conv_w + sum_k att[k]*weight[k] (bf16).
__global__ __launch_bounds__(256) void kW(const float* __restrict__ part,
                                          const float* __restrict__ nw0, const float* __restrict__ nb0,
                                          const float* __restrict__ nw1, const float* __restrict__ nb1,
                                          const float* __restrict__ nw2, const float* __restrict__ nb2,
                                          const float* __restrict__ weight,
                                          const float* __restrict__ convw,
                                          ushort_t* __restrict__ weff) {
    int bid = blockIdx.x;                 // n*9 + s
    int s = bid % 9;
    int n = bid / 9;
    int tid = threadIdx.x;

    __shared__ float cat_s[45];           // [cd][ch][st]
    __shared__ float box_s[45];
    __shared__ float tot_s;
    __shared__ float att_s[4];

    if (tid < 45) cat_s[tid] = 0.f;
    __syncthreads();
    if (tid < 128) {
        int h = tid;
        int ch = (h == 0) ? 0 : (h == 127) ? 2 : 1;
        const float* pp = part + (size_t)(n * 128 + h) * 16;
#pragma unroll
        for (int q = 0; q < 15; ++q) {
            int cd = q / 3, st = q % 3;
            atomicAdd(&cat_s[(cd * 3 + ch) * 3 + st], pp[q]);
        }
    }
    __syncthreads();

    if (tid < 46) {
        float c[5][3][3];
#pragma unroll
        for (int i = 0; i < 5; ++i)
#pragma unroll
            for (int j = 0; j < 3; ++j)
#pragma unroll
                for (int t = 0; t < 3; ++t)
                    c[i][j][t] = cat_s[(i * 3 + j) * 3 + t];

        if (tid < 45) {
            int dz = tid / 9 - 2;
            int dy = (tid / 3) % 3 - 1;
            int dx = tid % 3 - 1;
            float acc = 0.f;
#pragma unroll
            for (int cd = 0; cd < 5; ++cd) {
                int dv = (cd == 0) ? 0 : (cd == 1) ? 1 : (cd == 3) ? 62 : (cd == 4) ? 63 : -1;
                bool incd = (dv < 0) || (dv >= dz && dv < 64 + dz);
#pragma unroll
                for (int ch = 0; ch < 3; ++ch) {
                    int hv = (ch == 0) ? 0 : (ch == 2) ? 127 : -1;
                    bool inch = (hv < 0) || (hv >= dy && hv < 128 + dy);
                    if (incd && inch) {
                        float v = c[cd][ch][0];
                        if (dx == -1) v -= c[cd][ch][2];
                        else if (dx == 1) v -= c[cd][ch][1];
                        acc += v;
                    }
                }
            }
            box_s[tid] = acc;
        } else {
            float tot = 0.f;
#pragma unroll
            for (int i = 0; i < 5; ++i)
#pragma unroll
                for (int j = 0; j < 3; ++j) tot += c[i][j][0];
            tot_s = tot;
        }
    }
    __syncthreads();

    if (tid < 4) {
        int k = tid;
        const float invV = 1.0f / (64.f * 128.f * 128.f);
        float lg = nb0[k] + nb1[k] + nb2[k] + nw0[k] * tot_s * invV;
#pragma unroll
        for (int dz = 0; dz < 3; ++dz)
#pragma unroll
            for (int dy = 0; dy < 3; ++dy)
#pragma unroll
                for (int dx = 0; dx < 3; ++dx)
                    lg += nw1[k * 27 + dz * 9 + dy * 3 + dx] *
                          box_s[(dz + 1) * 9 + dy * 3 + dx] * invV;
#pragma unroll
        for (int b = 0; b < 45; ++b)
            lg += nw2[k * 45 + b] * box_s[b] * invV;

        float m = fmaxf(lg, __shfl_xor(lg, 1));
        m = fmaxf(m, __shfl_xor(m, 2));
        float e = __expf(lg - m);
        float ssum = e + __shfl_xor(e, 1);
        ssum += __shfl_xor(ssum, 2);
        att_s[k] = e / ssum;
    }
    __syncthreads();

    float a0 = att_s[0], a1 = att_s[1], a2 = att_s[2], a3 = att_s[3];
    int ci = tid & 63;
    int cog = tid >> 6;
    ushort_t* wp = weff + ((size_t)(n * 9 + s) * 64) * 64;
#pragma unroll
    for (int p = 0; p < 16; ++p) {
        int co = cog * 16 + p;
        size_t base = (size_t)(co * 64 + ci) * 9 + s;
        float v = convw[base]
                + a0 * weight[base]
                + a1 * weight[base +     64 * 64 * 9]
                + a2 * weight[base + 2 * 64 * 64 * 9]
                + a3 * weight[base + 3 * 64 * 64 * 9];
        wp[(size_t)co * 64 + ci] = f2bf(v);
    }
}

// ---------------------------------------------------------------------------
// kC: main conv. Block = (n, h-quad, w-half): 64co x (4h x 64w) tile.
// Stages B directly from f32 x (NCHW): tasks of 8ci x 8w, aligned float4
// loads, in-register 8x8 transpose + f32->bf16, ds_write_b128.
// LDS: [r(6)][ci8(8)][chunk(81; 80 w used)][8ci] = 62208 B.
// w coverage: wg = w0-8 .. w0+71; reads use c = wg-(w0-8) in [7,72].
// Tiles are 8-aligned -> every tile fully in-bounds or fully zero.
__global__ __launch_bounds__(256, 2) void kC(const float* __restrict__ x,
                                             const ushort_t* __restrict__ weff,
                                             const float* __restrict__ convb,
                                             float* __restrict__ out) {
    int bid = blockIdx.x;                 // (n*32 + hq)*2 + wt
    int whalf = bid & 1;
    int hq = (bid >> 1) & 31;
    int n = bid >> 6;
    int h0 = hq * 4;
    int w0 = whalf * 64;

    __shared__ __align__(16) ushort_t lds[6 * 8 * 81 * 8];   // 62208 B

    int tid = threadIdx.x;
    int lane = tid & 63;
    int wave = tid >> 6;                  // co tile
    int kq = lane >> 4;                   // quad 0..3
    int l15 = lane & 15;

    // ---- stage: 480 tasks (r 0..5, wt 0..9, ci8 0..7), ci8 fastest
    for (int t = tid; t < 480; t += 256) {
        int ci8 = t & 7;
        int rwt = t >> 3;
        int wt = rwt % 10;
        int r = rwt / 10;
        int hg = h0 + r - 1;
        int wg0 = w0 - 8 + wt * 8;
        float f[8][8];
        if (hg >= 0 && hg < 128 && wg0 >= 0 && wg0 <= 120) {
            const float* xp = x + ((size_t)(n * 64 + ci8 * 8) * 128 + hg) * 128 + wg0;
#pragma unroll
            for (int j = 0; j < 8; ++j) {
                float4 a = *(const float4*)(xp + (size_t)j * 16384);
                float4 b = *(const float4*)(xp + (size_t)j * 16384 + 4);
                f[j][0] = a.x; f[j][1] = a.y; f[j][2] = a.z; f[j][3] = a.w;
                f[j][4] = b.x; f[j][5] = b.y; f[j][6] = b.z; f[j][7] = b.w;
            }
        } else {
#pragma unroll
            for (int j = 0; j < 8; ++j)
#pragma unroll
                for (int e = 0; e < 8; ++e) f[j][e] = 0.f;
        }
        ushort_t* dst = &lds[(((size_t)r * 8 + ci8) * 81 + wt * 8) * 8];
#pragma unroll
        for (int e = 0; e < 8; ++e) {
            uint4 pk;
            pk.x = (unsigned)f2bf(f[0][e]) | ((unsigned)f2bf(f[1][e]) << 16);
            pk.y = (unsigned)f2bf(f[2][e]) | ((unsigned)f2bf(f[3][e]) << 16);
            pk.z = (unsigned)f2bf(f[4][e]) | ((unsigned)f2bf(f[5][e]) << 16);
            pk.w = (unsigned)f2bf(f[6][e]) | ((unsigned)f2bf(f[7][e]) << 16);
            *(uint4*)(dst + e * 8) = pk;
        }
    }

    // ---- A fragments (Weff): 18 x 16B = 72 VGPRs
    int co_a = wave * 16 + l15;
    bf16x8 afrag[9][2];
#pragma unroll
    for (int s = 0; s < 9; ++s)
#pragma unroll
        for (int kc = 0; kc < 2; ++kc)
            afrag[s][kc] = *(const bf16x8*)(weff +
                ((size_t)((n * 9 + s) * 64 + co_a)) * 64 + kc * 32 + kq * 8);

    f32x4 acc[16];
#pragma unroll
    for (int t = 0; t < 16; ++t) acc[t] = (f32x4){0.f, 0.f, 0.f, 0.f};

    __syncthreads();

    // ---- inner: register-cached B rows; 6 ds_read_b128 feed 12 MFMAs
#pragma unroll
    for (int kx = 0; kx < 3; ++kx) {
#pragma unroll
        for (int kc = 0; kc < 2; ++kc) {
#pragma unroll
            for (int col = 0; col < 4; ++col) {
                bf16x8 brow[6];
#pragma unroll
                for (int p = 0; p < 6; ++p)
                    brow[p] = *(const bf16x8*)
                        &lds[(((size_t)p * 8 + kc * 4 + kq) * 81 +
                              col * 16 + l15 + kx + 7) * 8];
#pragma unroll
                for (int ky = 0; ky < 3; ++ky)
#pragma unroll
                    for (int r = 0; r < 4; ++r)
                        acc[r * 4 + col] = __builtin_amdgcn_mfma_f32_16x16x32_bf16(
                            afrag[ky * 3 + kx][kc], brow[r + ky], acc[r * 4 + col], 0, 0, 0);
            }
        }
    }

    // ---- epilogue: D row(=co) = kq*4+reg, col(=w) = l15
#pragma unroll
    for (int r = 0; r < 4; ++r) {
        int h = h0 + r;
#pragma unroll
        for (int col = 0; col < 4; ++col) {
            int w = w0 + col * 16 + l15;
#pragma unroll
            for (int reg = 0; reg < 4; ++reg) {
                int co = wave * 16 + kq * 4 + reg;
                float v = acc[r * 4 + col][reg] + convb[co];
                out[(((size_t)n * 64 + co) * 128 + h) * 128 + w] = v;
            }
        }
    }
}

// ---------------------------------------------------------------------------
extern "C" void kernel_launch(void* const* d_in, const int* in_sizes, int n_in,
                              void* d_out, int out_size, void* d_ws, size_t ws_size,
                              hipStream_t stream) {
    const float* x      = (const float*)d_in[0];
    const float* weight = (const float*)d_in[1];
    const float* conv_w = (const float*)d_in[2];
    const float* conv_b = (const float*)d_in[3];
    const float* n0w    = (const float*)d_in[4];
    const float* n0b    = (const float*)d_in[5];
    const float* n1w    = (const float*)d_in[6];
    const float* n1b    = (const float*)d_in[7];
    const float* n2w    = (const float*)d_in[8];
    const float* n2b    = (const float*)d_in[9];
    float* out = (float*)d_out;

    char* ws = (char*)d_ws;
    ushort_t* weff = (ushort_t*)(ws);                  // 589824 B
    float*    part = (float*)(ws + 589824);            // 65536 B

    kR<<<1024, 256, 0, stream>>>(x, part);
    kW<<<72, 256, 0, stream>>>(part, n0w, n0b, n1w, n1b, n2w, n2b,
                               weight, conv_w, weff);
    kC<<<512, 256, 0, stream>>>(x, weff, conv_b, out);
}

// Round 8
// 132.823 us; speedup vs baseline: 1.0178x; 1.0178x over previous
//
#include <hip/hip_runtime.h>

// CondConv2d: N=8, C_IN=C_OUT=64, H=W=128, K=4 experts, 3x3, pad 1, stride 1.
// f32 in/out; bf16 MFMA compute with f32 accumulate.
// Identity: out = conv2d(x, conv_w + sum_k att[n,k]*weight[k]) + conv_b
// Routing logits = closed-form box-sums of x (mean-pooled C=1 3D convs).
// Pipeline (3 dispatches, no memset):
//   kTR: transpose x -> xt (bf16 [n][h][ci8][w][8ci]) + per-row stats -> part
//   kW : reduce part -> att -> Weff[n][s][co][ci] bf16
//   kC : MFMA conv, 64co x (4h x 64w) tiles, register-cached B rows.
// XCD affinity: all kernels decode n = blockIdx & 7, so each XCD (blockIdx%8
// round-robin) owns one sample; xt slice (2 MB) stays in that XCD's 4 MB L2.
// NOTE (R5): hipLaunchCooperativeKernel fails under harness graph capture.
// NOTE (R7): staging kC from f32 x directly regressed (-3.3 us) — keep xt.

typedef unsigned short ushort_t;
typedef __attribute__((ext_vector_type(8))) short bf16x8;
typedef __attribute__((ext_vector_type(4))) float f32x4;

__device__ __forceinline__ ushort_t f2bf(float f) {
    unsigned u = __float_as_uint(f);
    unsigned r = (u + 0x7fffu + ((u >> 16) & 1u)) >> 16;   // RNE
    return (ushort_t)r;
}

// ---------------------------------------------------------------------------
// kTR: block per (n,h), n = bid&7 (XCD affinity). Thread (ci8=tid>>5, wg=tid&31)
// loads 8ci x 4w scalar dwords (coalesced), packs bf16x8, writes xt 16B chunks.
// Per-row routing stats -> part[row*16 + cd*3+st] (no global atomics).
__global__ __launch_bounds__(256) void kTR(const float* __restrict__ x,
                                           ushort_t* __restrict__ xt,
                                           float* __restrict__ part) {
    int bid = blockIdx.x;                 // 1024
    int n = bid & 7, h = bid >> 3;
    int row = n * 128 + h;
    int tid = threadIdx.x;
    int wg = tid & 31;                    // w lane (w = wg + 32c)
    int ci8 = tid >> 5;                   // 0..7

    __shared__ float catloc[15];
    if (tid < 15) catloc[tid] = 0.f;
    __syncthreads();

    const float* xp = x + (size_t)(n * 64 + ci8 * 8) * 16384 + h * 128 + wg;
    float v[8][4];
#pragma unroll
    for (int j = 0; j < 8; ++j)
#pragma unroll
        for (int c = 0; c < 4; ++c)
            v[j][c] = xp[j * 16384 + c * 32];

    // xt writes: [n][h][ci8][w][8ci]
    ushort_t* op = xt + ((size_t)(row * 8 + ci8)) * 128 * 8;
#pragma unroll
    for (int c = 0; c < 4; ++c) {
        ushort_t u[8];
#pragma unroll
        for (int j = 0; j < 8; ++j) u[j] = f2bf(v[j][c]);
        uint4 pk;
        pk.x = (unsigned)u[0] | ((unsigned)u[1] << 16);
        pk.y = (unsigned)u[2] | ((unsigned)u[3] << 16);
        pk.z = (unsigned)u[4] | ((unsigned)u[5] << 16);
        pk.w = (unsigned)u[6] | ((unsigned)u[7] << 16);
        *(uint4*)(op + (size_t)(wg + c * 32) * 8) = pk;
    }

    // routing sums: per-ci row sum + boundary cols
#pragma unroll
    for (int j = 0; j < 8; ++j) {
        float rs = v[j][0] + v[j][1] + v[j][2] + v[j][3];
#pragma unroll
        for (int m = 1; m <= 16; m <<= 1) rs += __shfl_xor(rs, m);
        int ci = ci8 * 8 + j;
        int cd = (ci == 0) ? 0 : (ci == 1) ? 1 : (ci == 62) ? 3 : (ci == 63) ? 4 : 2;
        if (wg == 0) {
            atomicAdd(&catloc[cd * 3 + 0], rs);
            atomicAdd(&catloc[cd * 3 + 1], v[j][0]);            // w == 0
        }
        if (wg == 31) atomicAdd(&catloc[cd * 3 + 2], v[j][3]);  // w == 127
    }
    __syncthreads();
    if (tid < 15) part[row * 16 + tid] = catloc[tid];
}

// ---------------------------------------------------------------------------
// kW: block per (n,s), n = bid&7, s = bid>>3 (72 blocks). Reduce part -> cat;
// 45 box-sums in parallel; logits+softmax; Weff = conv_w + sum_k att*weight.
__global__ __launch_bounds__(256) void kW(const float* __restrict__ part,
                                          const float* __restrict__ nw0, const float* __restrict__ nb0,
                                          const float* __restrict__ nw1, const float* __restrict__ nb1,
                                          const float* __restrict__ nw2, const float* __restrict__ nb2,
                                          const float* __restrict__ weight,
                                          const float* __restrict__ convw,
                                          ushort_t* __restrict__ weff) {
    int bid = blockIdx.x;                 // 72: n = bid&7, s = bid>>3
    int n = bid & 7;
    int s = bid >> 3;
    int tid = threadIdx.x;

    __shared__ float cat_s[45];           // [cd][ch][st]
    __shared__ float box_s[45];
    __shared__ float tot_s;
    __shared__ float att_s[4];

    if (tid < 45) cat_s[tid] = 0.f;
    __syncthreads();
    if (tid < 128) {
        int h = tid;
        int ch = (h == 0) ? 0 : (h == 127) ? 2 : 1;
        const float* pp = part + (size_t)(n * 128 + h) * 16;
#pragma unroll
        for (int q = 0; q < 15; ++q) {
            int cd = q / 3, st = q % 3;
            atomicAdd(&cat_s[(cd * 3 + ch) * 3 + st], pp[q]);
        }
    }
    __syncthreads();

    if (tid < 46) {
        float c[5][3][3];
#pragma unroll
        for (int i = 0; i < 5; ++i)
#pragma unroll
            for (int j = 0; j < 3; ++j)
#pragma unroll
                for (int t = 0; t < 3; ++t)
                    c[i][j][t] = cat_s[(i * 3 + j) * 3 + t];

        if (tid < 45) {
            int dz = tid / 9 - 2;
            int dy = (tid / 3) % 3 - 1;
            int dx = tid % 3 - 1;
            float acc = 0.f;
#pragma unroll
            for (int cd = 0; cd < 5; ++cd) {
                int dv = (cd == 0) ? 0 : (cd == 1) ? 1 : (cd == 3) ? 62 : (cd == 4) ? 63 : -1;
                bool incd = (dv < 0) || (dv >= dz && dv < 64 + dz);
#pragma unroll
                for (int ch = 0; ch < 3; ++ch) {
                    int hv = (ch == 0) ? 0 : (ch == 2) ? 127 : -1;
                    bool inch = (hv < 0) || (hv >= dy && hv < 128 + dy);
                    if (incd && inch) {
                        float v = c[cd][ch][0];
                        if (dx == -1) v -= c[cd][ch][2];
                        else if (dx == 1) v -= c[cd][ch][1];
                        acc += v;
                    }
                }
            }
            box_s[tid] = acc;
        } else {
            float tot = 0.f;
#pragma unroll
            for (int i = 0; i < 5; ++i)
#pragma unroll
                for (int j = 0; j < 3; ++j) tot += c[i][j][0];
            tot_s = tot;
        }
    }
    __syncthreads();

    if (tid < 4) {
        int k = tid;
        const float invV = 1.0f / (64.f * 128.f * 128.f);
        float lg = nb0[k] + nb1[k] + nb2[k] + nw0[k] * tot_s * invV;
#pragma unroll
        for (int dz = 0; dz < 3; ++dz)
#pragma unroll
            for (int dy = 0; dy < 3; ++dy)
#pragma unroll
                for (int dx = 0; dx < 3; ++dx)
                    lg += nw1[k * 27 + dz * 9 + dy * 3 + dx] *
                          box_s[(dz + 1) * 9 + dy * 3 + dx] * invV;
#pragma unroll
        for (int b = 0; b < 45; ++b)
            lg += nw2[k * 45 + b] * box_s[b] * invV;

        float m = fmaxf(lg, __shfl_xor(lg, 1));
        m = fmaxf(m, __shfl_xor(m, 2));
        float e = __expf(lg - m);
        float ssum = e + __shfl_xor(e, 1);
        ssum += __shfl_xor(ssum, 2);
        att_s[k] = e / ssum;
    }
    __syncthreads();

    float a0 = att_s[0], a1 = att_s[1], a2 = att_s[2], a3 = att_s[3];
    int ci = tid & 63;
    int cog = tid >> 6;
    ushort_t* wp = weff + ((size_t)(n * 9 + s) * 64) * 64;
#pragma unroll
    for (int p = 0; p < 16; ++p) {
        int co = cog * 16 + p;
        size_t base = (size_t)(co * 64 + ci) * 9 + s;
        float v = convw[base]
                + a0 * weight[base]
                + a1 * weight[base +     64 * 64 * 9]
                + a2 * weight[base + 2 * 64 * 64 * 9]
                + a3 * weight[base + 3 * 64 * 64 * 9];
        wp[(size_t)co * 64 + ci] = f2bf(v);
    }
}

// ---------------------------------------------------------------------------
// kC: main conv. Block = (n, h-quad, w-half), n = bid&7 (XCD affinity).
// 64co x (4h x 64w) tile. LDS halo: 6 rows x [ci8(8)][66 w][8ci] = 50688 B.
// A (Weff) in registers. Inner: per (kx,kc,col) 6 ds_read_b128 feed 12 MFMAs.
__global__ __launch_bounds__(256, 2) void kC(const ushort_t* __restrict__ xt,
                                             const ushort_t* __restrict__ weff,
                                             const float* __restrict__ convb,
                                             float* __restrict__ out) {
    int bid = blockIdx.x;                 // 512: n = bid&7, rest = bid>>3
    int n = bid & 7;
    int rest = bid >> 3;                  // 0..63
    int wt = rest & 1;
    int hq = rest >> 1;                   // 0..31
    int h0 = hq * 4;
    int w0 = wt * 64;

    __shared__ __align__(16) ushort_t lds[6 * 8 * 66 * 8];   // 50688 B

    int tid = threadIdx.x;
    int lane = tid & 63;
    int wave = tid >> 6;                  // co tile
    int kq = lane >> 4;                   // quad 0..3
    int l15 = lane & 15;

    // stage halo: rows h0-1..h0+4; idx = (r*8 + ci8)*66 + c; 3168 x 16B
    for (int idx = tid; idx < 3168; idx += 256) {
        int c = idx % 66;
        int rc8 = idx / 66;
        int r = rc8 >> 3, ci8 = rc8 & 7;
        int hg = h0 + r - 1;
        int wg = w0 + c - 1;
        uint4 vv = make_uint4(0u, 0u, 0u, 0u);
        if (hg >= 0 && hg < 128 && wg >= 0 && wg < 128)
            vv = *(const uint4*)(xt + ((size_t)((n * 128 + hg) * 8 + ci8) * 128 + wg) * 8);
        *(uint4*)&lds[(size_t)idx * 8] = vv;
    }

    // A fragments (Weff): 18 x 16B = 72 VGPRs
    int co_a = wave * 16 + l15;
    bf16x8 afrag[9][2];
#pragma unroll
    for (int s = 0; s < 9; ++s)
#pragma unroll
        for (int kc = 0; kc < 2; ++kc)
            afrag[s][kc] = *(const bf16x8*)(weff +
                ((size_t)((n * 9 + s) * 64 + co_a)) * 64 + kc * 32 + kq * 8);

    f32x4 acc[16];
#pragma unroll
    for (int t = 0; t < 16; ++t) acc[t] = (f32x4){0.f, 0.f, 0.f, 0.f};

    __syncthreads();

    // inner: register-cached B rows
#pragma unroll
    for (int kx = 0; kx < 3; ++kx) {
#pragma unroll
        for (int kc = 0; kc < 2; ++kc) {
#pragma unroll
            for (int col = 0; col < 4; ++col) {
                bf16x8 brow[6];
#pragma unroll
                for (int p = 0; p < 6; ++p)
                    brow[p] = *(const bf16x8*)
                        &lds[(((p * 8 + kc * 4 + kq) * 66) + col * 16 + l15 + kx) * 8];
#pragma unroll
                for (int ky = 0; ky < 3; ++ky)
#pragma unroll
                    for (int r = 0; r < 4; ++r)
                        acc[r * 4 + col] = __builtin_amdgcn_mfma_f32_16x16x32_bf16(
                            afrag[ky * 3 + kx][kc], brow[r + ky], acc[r * 4 + col], 0, 0, 0);
            }
        }
    }

    // epilogue: D row(=co) = kq*4+reg, col(=w) = l15
#pragma unroll
    for (int r = 0; r < 4; ++r) {
        int h = h0 + r;
#pragma unroll
        for (int col = 0; col < 4; ++col) {
            int w = w0 + col * 16 + l15;
#pragma unroll
            for (int reg = 0; reg < 4; ++reg) {
                int co = wave * 16 + kq * 4 + reg;
                float v = acc[r * 4 + col][reg] + convb[co];
                out[(((size_t)n * 64 + co) * 128 + h) * 128 + w] = v;
            }
        }
    }
}

// ---------------------------------------------------------------------------
extern "C" void kernel_launch(void* const* d_in, const int* in_sizes, int n_in,
                              void* d_out, int out_size, void* d_ws, size_t ws_size,
                              hipStream_t stream) {
    const float* x      = (const float*)d_in[0];
    const float* weight = (const float*)d_in[1];
    const float* conv_w = (const float*)d_in[2];
    const float* conv_b = (const float*)d_in[3];
    const float* n0w    = (const float*)d_in[4];
    const float* n0b    = (const float*)d_in[5];
    const float* n1w    = (const float*)d_in[6];
    const float* n1b    = (const float*)d_in[7];
    const float* n2w    = (const float*)d_in[8];
    const float* n2b    = (const float*)d_in[9];
    float* out = (float*)d_out;

    char* ws = (char*)d_ws;
    ushort_t* xt   = (ushort_t*)(ws);                      // 16 MB
    ushort_t* weff = (ushort_t*)(ws + 16777216);           // 589824 B
    float*    part = (float*)(ws + 16777216 + 589824);     // 65536 B

    kTR<<<1024, 256, 0, stream>>>(x, xt, part);
    kW<<<72, 256, 0, stream>>>(part, n0w, n0b, n1w, n1b, n2w, n2b,
                               weight, conv_w, weff);
    kC<<<512, 256, 0, stream>>>(xt, weff, conv_b, out);
}